// Round 9
// baseline (420.585 us; speedup 1.0000x reference)
//
#include <hip/hip_runtime.h>

#define EPS 1e-8f

__device__ inline unsigned short f2bf(float f) {           // RNE fp32->bf16
    unsigned u = __float_as_uint(f);
    unsigned r = u + 0x7fffu + ((u >> 16) & 1u);
    return (unsigned short)(r >> 16);
}
__device__ inline float bflo(unsigned v) { return __uint_as_float(v << 16); }
__device__ inline float bfhi(unsigned v) { return __uint_as_float(v & 0xffff0000u); }

// ---------------------------------------------------------------------------
// FUSED Kernel A: fp32 GEMM (+score projections) with role-split dst-histogram
// blocks. 40KB LDS (Wt 32KB resident + 8KB x-chunks, 4/tile) -> 4 blocks/CU
// (was 64KB -> 2 blocks/CU, 18% occupancy, 29% VALUBusy: latency-bound).
// K-accumulation order identical to the 64KB version -> bit-identical
// hb/s_src/s_dst (validated in round 7's fused kernel).
// count role = word-granular atomics on a 0.4MB table (safe to co-schedule).
// ---------------------------------------------------------------------------
__global__ __launch_bounds__(256, 4) void gemm_count_kernel(
    const float* __restrict__ x, const float* __restrict__ W,
    const float* __restrict__ a_src, const float* __restrict__ a_dst,
    unsigned short* __restrict__ hb, float* __restrict__ s_src, float* __restrict__ s_dst,
    int N, int n_tiles,
    const int* __restrict__ dst, int* __restrict__ counts, int E)
{
    __shared__ float Wt[128 * 64];   // 32 KB
    __shared__ float xt[32 * 64];    //  8 KB

    const int bid = blockIdx.x;
    const int r3  = bid % 3;

    if (r3 == 2) {
        // ---------------- COUNT role (512 blocks) ----------------
        const int c = bid / 3;
        for (int e = c * 256 + threadIdx.x; e < E; e += 512 * 256)
            atomicAdd(counts + dst[e], 1);
        return;
    }

    // ---------------- GEMM role (1024 blocks) ----------------
    const int g    = (bid / 3) * 2 + r3;   // 0..1023
    const int half = g >> 9;               // 0/1
    const int bx   = g & 511;
    const int t    = threadIdx.x;
    const float* Wh = W + half * 64 * 128;

#pragma unroll
    for (int p = 0; p < 8; ++p) {
        int idx = p * 256 + t;
        int ol = (idx & 31) | ((idx >> 10) << 5);
        int k4 = (idx >> 5) & 31;
        float4 w = *(const float4*)(Wh + ol * 128 + k4 * 4);
        Wt[(4 * k4 + 0) * 64 + ol] = w.x;
        Wt[(4 * k4 + 1) * 64 + ol] = w.y;
        Wt[(4 * k4 + 2) * 64 + ol] = w.z;
        Wt[(4 * k4 + 3) * 64 + ol] = w.w;
    }
    __syncthreads();

    const int o4 = t & 15;
    const int n4g = t >> 4;
    const int head = half * 2 + (o4 >> 3);
    const float4 as = *(const float4*)(a_src + head * 32 + (o4 & 7) * 4);
    const float4 ad = *(const float4*)(a_dst + head * 32 + (o4 & 7) * 4);

    for (int tile = bx; tile < n_tiles; tile += 512) {
        const int nbase = tile * 64;

        float acc[4][4];
#pragma unroll
        for (int i = 0; i < 4; ++i)
#pragma unroll
            for (int j = 0; j < 4; ++j) acc[i][j] = 0.f;

        for (int kc = 0; kc < 4; ++kc) {
            __syncthreads();
#pragma unroll
            for (int p = 0; p < 2; ++p) {
                int idx = p * 256 + t;
                int n = idx & 63;
                int k4 = idx >> 6;           // 0..7
                int ng = nbase + n;
                float4 v = make_float4(0.f, 0.f, 0.f, 0.f);
                if (ng < N) v = *(const float4*)(x + (size_t)ng * 128 + kc * 32 + k4 * 4);
                xt[(4 * k4 + 0) * 64 + n] = v.x;
                xt[(4 * k4 + 1) * 64 + n] = v.y;
                xt[(4 * k4 + 2) * 64 + n] = v.z;
                xt[(4 * k4 + 3) * 64 + n] = v.w;
            }
            __syncthreads();

            for (int k = 0; k < 32; ++k) {
                float4 wv = *(const float4*)(Wt + (kc * 32 + k) * 64 + 4 * o4);
                float4 xv = *(const float4*)(xt + k * 64 + 4 * n4g);
                float wa[4] = {wv.x, wv.y, wv.z, wv.w};
                float xa[4] = {xv.x, xv.y, xv.z, xv.w};
#pragma unroll
                for (int i = 0; i < 4; ++i)
#pragma unroll
                    for (int j = 0; j < 4; ++j) acc[i][j] += xa[i] * wa[j];
            }
        }

#pragma unroll
        for (int i = 0; i < 4; ++i) {
            int n = nbase + 4 * n4g + i;
            float ps = acc[i][0] * as.x + acc[i][1] * as.y + acc[i][2] * as.z + acc[i][3] * as.w;
            float pd = acc[i][0] * ad.x + acc[i][1] * ad.y + acc[i][2] * ad.z + acc[i][3] * ad.w;
            ps += __shfl_xor(ps, 1); ps += __shfl_xor(ps, 2); ps += __shfl_xor(ps, 4);
            pd += __shfl_xor(pd, 1); pd += __shfl_xor(pd, 2); pd += __shfl_xor(pd, 4);
            if (n < N) {
                ushort4 hv;
                hv.x = f2bf(acc[i][0]); hv.y = f2bf(acc[i][1]);
                hv.z = f2bf(acc[i][2]); hv.w = f2bf(acc[i][3]);
                *(ushort4*)(hb + (size_t)n * 128 + half * 64 + 4 * o4) = hv;
                if ((o4 & 7) == 0) {
                    s_src[n * 4 + head] = ps;
                    s_dst[n * 4 + head] = pd;
                }
            }
        }
    }
}

// ---------------------------------------------------------------------------
// CSR build: 2-level exclusive scan (scan2 parallel — round-8 proven).
// ---------------------------------------------------------------------------
__global__ __launch_bounds__(256) void scan1_kernel(
    const int* __restrict__ counts, int* __restrict__ offs, int* __restrict__ bsum, int N)
{
    __shared__ int sh[256];
    int t = threadIdx.x;
    int base = blockIdx.x * 1024 + t * 4;
    int c[4];
#pragma unroll
    for (int j = 0; j < 4; ++j) c[j] = (base + j < N) ? counts[base + j] : 0;
    int tsum = c[0] + c[1] + c[2] + c[3];
    sh[t] = tsum;
    __syncthreads();
    for (int off = 1; off < 256; off <<= 1) {
        int v = (t >= off) ? sh[t - off] : 0;
        __syncthreads();
        sh[t] += v;
        __syncthreads();
    }
    int run = sh[t] - tsum;  // exclusive
    if (t == 255) bsum[blockIdx.x] = sh[255];
#pragma unroll
    for (int j = 0; j < 4; ++j) {
        if (base + j < N) { offs[base + j] = run; run += c[j]; }
    }
}

__global__ __launch_bounds__(512) void scan2_kernel(int* __restrict__ bsum, int nb)
{
    __shared__ int sh[512];
    int t = threadIdx.x;
    if (nb <= 512) {
        int v = (t < nb) ? bsum[t] : 0;
        sh[t] = v;
        __syncthreads();
        for (int off = 1; off < 512; off <<= 1) {
            int u = (t >= off) ? sh[t - off] : 0;
            __syncthreads();
            sh[t] += u;
            __syncthreads();
        }
        if (t < nb) bsum[t] = sh[t] - v;   // exclusive
    } else if (t == 0) {                    // fallback (not hit at N=100000)
        int acc = 0;
        for (int i = 0; i < nb; ++i) { int v = bsum[i]; bsum[i] = acc; acc += v; }
    }
}

__global__ __launch_bounds__(256) void scan3_kernel(
    int* __restrict__ offs, const int* __restrict__ bsum,
    int* __restrict__ cursor, int N)
{
    int i = blockIdx.x * 256 + threadIdx.x;
    if (i >= N) return;
    int v = offs[i] + bsum[i >> 10];
    offs[i] = v;
    cursor[i] = v;
}

// ---------------------------------------------------------------------------
// XCD-sharded packing scatter (round-6 proven, UNCHANGED, runs ALONE:
// its 1.6MB/shard rec window needs a quiet L2 — round-7 lesson).
// Record = {src, lw=log(rnbrw+EPS)}.
// ---------------------------------------------------------------------------
__global__ __launch_bounds__(256) void scatter_kernel(
    const int* __restrict__ src, const int* __restrict__ dst,
    const float* __restrict__ rnbrw,
    int* __restrict__ cursor, int2* __restrict__ rec,
    int E, int ssz, int bps)
{
    const int shard = blockIdx.x & 7;
    const int j = blockIdx.x >> 3;
    const int lo = shard * ssz;
    const int hi = lo + ssz;
    const int stride = bps * 256;
    for (int base = j * 256; base < E; base += stride) {
        int e = base + threadIdx.x;
        if (e < E) {
            int d = dst[e];
            if (d >= lo && d < hi) {
                float lw = __logf(rnbrw[e] + EPS);
                int pos = atomicAdd(cursor + d, 1);
                rec[pos] = make_int2(src[e], __float_as_int(lw));
            }
        }
    }
}

// ---------------------------------------------------------------------------
// Kernel C: per-node aggregation with on-the-fly es recompute (round-6
// proven: 78us, FETCH 242MB). Unchanged.
// ---------------------------------------------------------------------------
__global__ __launch_bounds__(256) void node_aggr_kernel(
    const int* __restrict__ offs, const int* __restrict__ counts,
    const int2* __restrict__ rec,
    const float* __restrict__ s_src, const float* __restrict__ s_dst,
    const unsigned short* __restrict__ hb,
    float* __restrict__ inv_den, float* __restrict__ out, int N)
{
    int gid = blockIdx.x * 256 + threadIdx.x;
    int n = gid >> 5;
    int l = gid & 31;
    if (n >= N) return;

    const int q    = l & 15;
    const int half = l >> 4;
    const int head = q >> 2;

    const int beg = offs[n];
    const int cnt = counts[n];
    const float sdn = s_dst[n * 4 + head];

    float a0 = 0.f, a1 = 0.f, a2 = 0.f, a3 = 0.f;
    float a4 = 0.f, a5 = 0.f, a6 = 0.f, a7 = 0.f;
    float den = 0.f;

    for (int i = 0; i < cnt; i += 4) {
        int j0 = i + half;
        int j1 = i + 2 + half;
        int jc0 = (j0 < cnt) ? j0 : 0;      // clamp; contribution masked below
        int jc1 = (j1 < cnt) ? j1 : 0;
        int2 r0 = rec[(size_t)beg + jc0];   // same addr across 16-lane half
        int2 r1 = rec[(size_t)beg + jc1];
        uint4 v0 = *(const uint4*)(hb + (size_t)r0.x * 128 + q * 8);
        uint4 v1 = *(const uint4*)(hb + (size_t)r1.x * 128 + q * 8);
        // same op order as alpha_kernel: (ssrc + sdst) + lw
        float t0 = s_src[(size_t)r0.x * 4 + head] + sdn + __int_as_float(r0.y);
        float t1 = s_src[(size_t)r1.x * 4 + head] + sdn + __int_as_float(r1.y);
        t0 = (t0 >= 0.f) ? t0 : 0.2f * t0;
        t1 = (t1 >= 0.f) ? t1 : 0.2f * t1;
        float e0 = __expf(t0);
        float e1 = __expf(t1);
        if (j0 >= cnt) e0 = 0.f;
        if (j1 >= cnt) e1 = 0.f;
        a0 += e0 * bflo(v0.x); a1 += e0 * bfhi(v0.x);
        a2 += e0 * bflo(v0.y); a3 += e0 * bfhi(v0.y);
        a4 += e0 * bflo(v0.z); a5 += e0 * bfhi(v0.z);
        a6 += e0 * bflo(v0.w); a7 += e0 * bfhi(v0.w);
        a0 += e1 * bflo(v1.x); a1 += e1 * bfhi(v1.x);
        a2 += e1 * bflo(v1.y); a3 += e1 * bfhi(v1.y);
        a4 += e1 * bflo(v1.z); a5 += e1 * bfhi(v1.z);
        a6 += e1 * bflo(v1.w); a7 += e1 * bfhi(v1.w);
        den += e0 + e1;
    }

    // combine the two halves (each processed every other edge)
    a0 += __shfl_xor(a0, 16, 32); a1 += __shfl_xor(a1, 16, 32);
    a2 += __shfl_xor(a2, 16, 32); a3 += __shfl_xor(a3, 16, 32);
    a4 += __shfl_xor(a4, 16, 32); a5 += __shfl_xor(a5, 16, 32);
    a6 += __shfl_xor(a6, 16, 32); a7 += __shfl_xor(a7, 16, 32);
    den += __shfl_xor(den, 16, 32);

    const float inv = 1.f / (den + EPS);

    // gather all 4 head denominators for the inv_den table (lane 0 stores)
    float d0 = __shfl(den, 0, 32);
    float d1 = __shfl(den, 4, 32);
    float d2 = __shfl(den, 8, 32);
    float d3 = __shfl(den, 12, 32);

    float4 o = half ? make_float4(a4 * inv, a5 * inv, a6 * inv, a7 * inv)
                    : make_float4(a0 * inv, a1 * inv, a2 * inv, a3 * inv);
    *(float4*)(out + (size_t)n * 128 + q * 8 + half * 4) = o;

    if (l == 0)
        *(float4*)(inv_den + (size_t)n * 4) =
            make_float4(1.f / (d0 + EPS), 1.f / (d1 + EPS),
                        1.f / (d2 + EPS), 1.f / (d3 + EPS));
}

// ---------------------------------------------------------------------------
// Kernel D: edge-order alpha, recomputed from the score tables (identical
// fp32 ops/order as node_aggr's es). Unchanged.
// ---------------------------------------------------------------------------
__global__ __launch_bounds__(256) void alpha_kernel(
    const int* __restrict__ src, const int* __restrict__ dst,
    const float* __restrict__ rnbrw,
    const float* __restrict__ s_src, const float* __restrict__ s_dst,
    const float* __restrict__ inv_den, float* __restrict__ alpha, int E)
{
    int e = blockIdx.x * 256 + threadIdx.x;
    if (e >= E) return;
    int s = src[e], d = dst[e];
    float lw = __logf(rnbrw[e] + EPS);
    float4 a = *(const float4*)(s_src + s * 4);
    float4 b = *(const float4*)(s_dst + d * 4);
    float4 iv = *(const float4*)(inv_den + (size_t)d * 4);
    float4 al;
    float v;
    v = a.x + b.x + lw; v = (v >= 0.f) ? v : 0.2f * v; al.x = __expf(v) * iv.x;
    v = a.y + b.y + lw; v = (v >= 0.f) ? v : 0.2f * v; al.y = __expf(v) * iv.y;
    v = a.z + b.z + lw; v = (v >= 0.f) ? v : 0.2f * v; al.z = __expf(v) * iv.z;
    v = a.w + b.w + lw; v = (v >= 0.f) ? v : 0.2f * v; al.w = __expf(v) * iv.w;
    *(float4*)(alpha + (size_t)e * 4) = al;
}

extern "C" void kernel_launch(void* const* d_in, const int* in_sizes, int n_in,
                              void* d_out, int out_size, void* d_ws, size_t ws_size,
                              hipStream_t stream) {
    const float* x      = (const float*)d_in[0];
    const float* W      = (const float*)d_in[1];
    const float* a_src  = (const float*)d_in[2];
    const float* a_dst  = (const float*)d_in[3];
    const int*   eidx   = (const int*)d_in[4];
    const float* rnbrw  = (const float*)d_in[5];

    const int E = in_sizes[5];           // 1600000
    const int N = in_sizes[0] / 128;     // 100000

    float* out   = (float*)d_out;                    // [N,128]
    float* alpha = out + (size_t)N * 128;            // [E,4] final alpha

    // Workspace layout (~44.5 MB, inside the proven 68.4 MB budget).
    char* w = (char*)d_ws;
    unsigned short* hb = (unsigned short*)w;  w += (size_t)N * 128 * 2;  // 25.6 MB
    int2* rec     = (int2*)w;                 w += (size_t)E * 8;        // 12.8 MB
    float* s_src  = (float*)w;                w += (size_t)N * 16;       //  1.6 MB
    float* s_dst  = (float*)w;                w += (size_t)N * 16;       //  1.6 MB
    float* inv_den = (float*)w;               w += (size_t)N * 16;       //  1.6 MB
    int* counts  = (int*)w;                   w += (size_t)N * 4;        //  0.4 MB
    int* offs    = (int*)w;                   w += (size_t)N * 4;        //  0.4 MB
    int* cursor  = (int*)w;                   w += (size_t)N * 4;        //  0.4 MB
    int* bsum    = (int*)w;                   w += 512 * 4;

    const int* src = eidx;
    const int* dst = eidx + E;

    hipMemsetAsync(counts, 0, (size_t)N * sizeof(int), stream);

    // One launch: 1024 gemm blocks + 512 count blocks, interleaved (bid%3)
    // so both roles co-reside from t=0. count hides under the VALU-bound gemm.
    int n_tiles = (N + 63) / 64;
    gemm_count_kernel<<<1536, 256, 0, stream>>>(
        x, W, a_src, a_dst, hb, s_src, s_dst, N, n_tiles, dst, counts, E);

    int nb = (N + 1023) / 1024;
    scan1_kernel<<<nb, 256, 0, stream>>>(counts, offs, bsum, N);
    scan2_kernel<<<1, 512, 0, stream>>>(bsum, nb);
    scan3_kernel<<<(N + 255) / 256, 256, 0, stream>>>(offs, bsum, cursor, N);

    // 8 shard classes x bps blocks; class s (intended XCD s) handles
    // dst in [s*ssz, (s+1)*ssz). Runs alone: needs a quiet L2.
    int ssz = (N + 7) / 8;
    int bps = 256;
    scatter_kernel<<<8 * bps, 256, 0, stream>>>(src, dst, rnbrw, cursor, rec, E, ssz, bps);

    int ablocks = ((size_t)N * 32 + 255) / 256;
    node_aggr_kernel<<<ablocks, 256, 0, stream>>>(offs, counts, rec, s_src, s_dst, hb,
                                                  inv_den, out, N);

    int eblocks = (E + 255) / 256;
    alpha_kernel<<<eblocks, 256, 0, stream>>>(src, dst, rnbrw, s_src, s_dst,
                                              inv_den, alpha, E);
}

// Round 10
// 384.694 us; speedup vs baseline: 1.0933x; 1.0933x over previous
//
#include <hip/hip_runtime.h>

#define EPS 1e-8f

__device__ inline unsigned short f2bf(float f) {           // RNE fp32->bf16
    unsigned u = __float_as_uint(f);
    unsigned r = u + 0x7fffu + ((u >> 16) & 1u);
    return (unsigned short)(r >> 16);
}
__device__ inline float bflo(unsigned v) { return __uint_as_float(v << 16); }
__device__ inline float bfhi(unsigned v) { return __uint_as_float(v & 0xffff0000u); }

// ---------------------------------------------------------------------------
// FUSED Kernel A: fp32 GEMM (+score projections) with role-split dst-histogram
// blocks. Round-8 64KB-LDS structure (proven 99us) + T14-style register
// prefetch: next tile's x is loaded into regs BEFORE the 128-deep FMA loop,
// committed to LDS at the next tile boundary -> HBM latency hides under FMA.
// FMA k-order unchanged -> bit-identical hb/s_src/s_dst.
// count role = word-granular atomics on a 0.4MB table (safe to co-schedule).
// ---------------------------------------------------------------------------
__global__ __launch_bounds__(256) void gemm_count_kernel(
    const float* __restrict__ x, const float* __restrict__ W,
    const float* __restrict__ a_src, const float* __restrict__ a_dst,
    unsigned short* __restrict__ hb, float* __restrict__ s_src, float* __restrict__ s_dst,
    int N, int n_tiles,
    const int* __restrict__ dst, int* __restrict__ counts, int E)
{
    __shared__ float Wt[128 * 64];   // 32 KB
    __shared__ float xt[128 * 64];   // 32 KB

    const int bid = blockIdx.x;
    const int r3  = bid % 3;

    if (r3 == 2) {
        // ---------------- COUNT role (512 blocks) ----------------
        const int c = bid / 3;
        for (int e = c * 256 + threadIdx.x; e < E; e += 512 * 256)
            atomicAdd(counts + dst[e], 1);
        return;
    }

    // ---------------- GEMM role (1024 blocks) ----------------
    const int g    = (bid / 3) * 2 + r3;   // 0..1023
    const int half = g >> 9;               // 0/1
    const int bx   = g & 511;
    const int t    = threadIdx.x;
    const float* Wh = W + half * 64 * 128;

#pragma unroll
    for (int p = 0; p < 8; ++p) {
        int idx = p * 256 + t;
        int ol = (idx & 31) | ((idx >> 10) << 5);
        int k4 = (idx >> 5) & 31;
        float4 w = *(const float4*)(Wh + ol * 128 + k4 * 4);
        Wt[(4 * k4 + 0) * 64 + ol] = w.x;
        Wt[(4 * k4 + 1) * 64 + ol] = w.y;
        Wt[(4 * k4 + 2) * 64 + ol] = w.z;
        Wt[(4 * k4 + 3) * 64 + ol] = w.w;
    }

    const int o4 = t & 15;
    const int n4g = t >> 4;
    const int head = half * 2 + (o4 >> 3);
    const float4 as = *(const float4*)(a_src + head * 32 + (o4 & 7) * 4);
    const float4 ad = *(const float4*)(a_dst + head * 32 + (o4 & 7) * 4);

    // register staging for the x tile (8 x float4 = 32 VGPR)
    float4 xr[8];

    // preload first tile into regs
    {
        const int nbase = bx * 64;
#pragma unroll
        for (int p = 0; p < 8; ++p) {
            int idx = p * 256 + t;
            int n = idx & 63;
            int k4 = idx >> 6;
            int ng = nbase + n;
            xr[p] = make_float4(0.f, 0.f, 0.f, 0.f);
            if (bx < n_tiles && ng < N)
                xr[p] = *(const float4*)(x + (size_t)ng * 128 + k4 * 4);
        }
    }

    for (int tile = bx; tile < n_tiles; tile += 512) {
        const int nbase = tile * 64;
        __syncthreads();              // xt free (previous FMA done) / Wt ready
#pragma unroll
        for (int p = 0; p < 8; ++p) {
            int idx = p * 256 + t;
            int n = idx & 63;
            int k4 = idx >> 6;
            xt[(4 * k4 + 0) * 64 + n] = xr[p].x;
            xt[(4 * k4 + 1) * 64 + n] = xr[p].y;
            xt[(4 * k4 + 2) * 64 + n] = xr[p].z;
            xt[(4 * k4 + 3) * 64 + n] = xr[p].w;
        }
        __syncthreads();              // xt ready

        // issue next tile's loads NOW -> they fly under the FMA loop
        {
            int nt2 = tile + 512;
            if (nt2 < n_tiles) {
                const int nb2 = nt2 * 64;
#pragma unroll
                for (int p = 0; p < 8; ++p) {
                    int idx = p * 256 + t;
                    int n = idx & 63;
                    int k4 = idx >> 6;
                    int ng = nb2 + n;
                    xr[p] = make_float4(0.f, 0.f, 0.f, 0.f);
                    if (ng < N)
                        xr[p] = *(const float4*)(x + (size_t)ng * 128 + k4 * 4);
                }
            }
        }

        float acc[4][4];
#pragma unroll
        for (int i = 0; i < 4; ++i)
#pragma unroll
            for (int j = 0; j < 4; ++j) acc[i][j] = 0.f;

        for (int k = 0; k < 128; ++k) {
            float4 wv = *(const float4*)(Wt + k * 64 + 4 * o4);
            float4 xv = *(const float4*)(xt + k * 64 + 4 * n4g);
            float wa[4] = {wv.x, wv.y, wv.z, wv.w};
            float xa[4] = {xv.x, xv.y, xv.z, xv.w};
#pragma unroll
            for (int i = 0; i < 4; ++i)
#pragma unroll
                for (int j = 0; j < 4; ++j) acc[i][j] += xa[i] * wa[j];
        }

#pragma unroll
        for (int i = 0; i < 4; ++i) {
            int n = nbase + 4 * n4g + i;
            float ps = acc[i][0] * as.x + acc[i][1] * as.y + acc[i][2] * as.z + acc[i][3] * as.w;
            float pd = acc[i][0] * ad.x + acc[i][1] * ad.y + acc[i][2] * ad.z + acc[i][3] * ad.w;
            ps += __shfl_xor(ps, 1); ps += __shfl_xor(ps, 2); ps += __shfl_xor(ps, 4);
            pd += __shfl_xor(pd, 1); pd += __shfl_xor(pd, 2); pd += __shfl_xor(pd, 4);
            if (n < N) {
                ushort4 hv;
                hv.x = f2bf(acc[i][0]); hv.y = f2bf(acc[i][1]);
                hv.z = f2bf(acc[i][2]); hv.w = f2bf(acc[i][3]);
                *(ushort4*)(hb + (size_t)n * 128 + half * 64 + 4 * o4) = hv;
                if ((o4 & 7) == 0) {
                    s_src[n * 4 + head] = ps;
                    s_dst[n * 4 + head] = pd;
                }
            }
        }
    }
}

// ---------------------------------------------------------------------------
// CSR build: 2-level exclusive scan (scan2 parallel — round-8 proven).
// ---------------------------------------------------------------------------
__global__ __launch_bounds__(256) void scan1_kernel(
    const int* __restrict__ counts, int* __restrict__ offs, int* __restrict__ bsum, int N)
{
    __shared__ int sh[256];
    int t = threadIdx.x;
    int base = blockIdx.x * 1024 + t * 4;
    int c[4];
#pragma unroll
    for (int j = 0; j < 4; ++j) c[j] = (base + j < N) ? counts[base + j] : 0;
    int tsum = c[0] + c[1] + c[2] + c[3];
    sh[t] = tsum;
    __syncthreads();
    for (int off = 1; off < 256; off <<= 1) {
        int v = (t >= off) ? sh[t - off] : 0;
        __syncthreads();
        sh[t] += v;
        __syncthreads();
    }
    int run = sh[t] - tsum;  // exclusive
    if (t == 255) bsum[blockIdx.x] = sh[255];
#pragma unroll
    for (int j = 0; j < 4; ++j) {
        if (base + j < N) { offs[base + j] = run; run += c[j]; }
    }
}

__global__ __launch_bounds__(512) void scan2_kernel(int* __restrict__ bsum, int nb)
{
    __shared__ int sh[512];
    int t = threadIdx.x;
    if (nb <= 512) {
        int v = (t < nb) ? bsum[t] : 0;
        sh[t] = v;
        __syncthreads();
        for (int off = 1; off < 512; off <<= 1) {
            int u = (t >= off) ? sh[t - off] : 0;
            __syncthreads();
            sh[t] += u;
            __syncthreads();
        }
        if (t < nb) bsum[t] = sh[t] - v;   // exclusive
    } else if (t == 0) {                    // fallback (not hit at N=100000)
        int acc = 0;
        for (int i = 0; i < nb; ++i) { int v = bsum[i]; bsum[i] = acc; acc += v; }
    }
}

__global__ __launch_bounds__(256) void scan3_kernel(
    int* __restrict__ offs, const int* __restrict__ bsum,
    int* __restrict__ cursor, int N)
{
    int i = blockIdx.x * 256 + threadIdx.x;
    if (i >= N) return;
    int v = offs[i] + bsum[i >> 10];
    offs[i] = v;
    cursor[i] = v;
}

// ---------------------------------------------------------------------------
// XCD-sharded packing scatter (round-6 geometry, runs ALONE: its 1.6MB/shard
// rec window needs a quiet L2 — round-7 lesson). Record = {src, lw}.
// New: int4 dst scan (4 edges/lane) — 4x fewer scan instructions, wider
// requests on the 8-pass stream. Window/record/atomic logic unchanged.
// ---------------------------------------------------------------------------
__global__ __launch_bounds__(256) void scatter_kernel(
    const int* __restrict__ src, const int* __restrict__ dst,
    const float* __restrict__ rnbrw,
    int* __restrict__ cursor, int2* __restrict__ rec,
    int E, int ssz, int bps)
{
    const int shard = blockIdx.x & 7;
    const int j = blockIdx.x >> 3;
    const int lo = shard * ssz;
    const int hi = lo + ssz;
    const int stride = bps * 1024;
    for (int base = j * 1024; base < E; base += stride) {
        int e0 = base + threadIdx.x * 4;
        if (e0 + 3 < E) {
            int4 d4 = *(const int4*)(dst + e0);
            int da[4] = {d4.x, d4.y, d4.z, d4.w};
#pragma unroll
            for (int c = 0; c < 4; ++c) {
                int d = da[c];
                if (d >= lo && d < hi) {
                    int e = e0 + c;
                    float lw = __logf(rnbrw[e] + EPS);
                    int pos = atomicAdd(cursor + d, 1);
                    rec[pos] = make_int2(src[e], __float_as_int(lw));
                }
            }
        } else {
            for (int e = e0; e < E; ++e) {
                int d = dst[e];
                if (d >= lo && d < hi) {
                    float lw = __logf(rnbrw[e] + EPS);
                    int pos = atomicAdd(cursor + d, 1);
                    rec[pos] = make_int2(src[e], __float_as_int(lw));
                }
            }
        }
    }
}

// ---------------------------------------------------------------------------
// Kernel C: per-node aggregation with on-the-fly es recompute (round-6
// proven: 78us, FETCH 242MB). Unchanged.
// ---------------------------------------------------------------------------
__global__ __launch_bounds__(256) void node_aggr_kernel(
    const int* __restrict__ offs, const int* __restrict__ counts,
    const int2* __restrict__ rec,
    const float* __restrict__ s_src, const float* __restrict__ s_dst,
    const unsigned short* __restrict__ hb,
    float* __restrict__ inv_den, float* __restrict__ out, int N)
{
    int gid = blockIdx.x * 256 + threadIdx.x;
    int n = gid >> 5;
    int l = gid & 31;
    if (n >= N) return;

    const int q    = l & 15;
    const int half = l >> 4;
    const int head = q >> 2;

    const int beg = offs[n];
    const int cnt = counts[n];
    const float sdn = s_dst[n * 4 + head];

    float a0 = 0.f, a1 = 0.f, a2 = 0.f, a3 = 0.f;
    float a4 = 0.f, a5 = 0.f, a6 = 0.f, a7 = 0.f;
    float den = 0.f;

    for (int i = 0; i < cnt; i += 4) {
        int j0 = i + half;
        int j1 = i + 2 + half;
        int jc0 = (j0 < cnt) ? j0 : 0;      // clamp; contribution masked below
        int jc1 = (j1 < cnt) ? j1 : 0;
        int2 r0 = rec[(size_t)beg + jc0];   // same addr across 16-lane half
        int2 r1 = rec[(size_t)beg + jc1];
        uint4 v0 = *(const uint4*)(hb + (size_t)r0.x * 128 + q * 8);
        uint4 v1 = *(const uint4*)(hb + (size_t)r1.x * 128 + q * 8);
        // same op order as alpha_kernel: (ssrc + sdst) + lw
        float t0 = s_src[(size_t)r0.x * 4 + head] + sdn + __int_as_float(r0.y);
        float t1 = s_src[(size_t)r1.x * 4 + head] + sdn + __int_as_float(r1.y);
        t0 = (t0 >= 0.f) ? t0 : 0.2f * t0;
        t1 = (t1 >= 0.f) ? t1 : 0.2f * t1;
        float e0 = __expf(t0);
        float e1 = __expf(t1);
        if (j0 >= cnt) e0 = 0.f;
        if (j1 >= cnt) e1 = 0.f;
        a0 += e0 * bflo(v0.x); a1 += e0 * bfhi(v0.x);
        a2 += e0 * bflo(v0.y); a3 += e0 * bfhi(v0.y);
        a4 += e0 * bflo(v0.z); a5 += e0 * bfhi(v0.z);
        a6 += e0 * bflo(v0.w); a7 += e0 * bfhi(v0.w);
        a0 += e1 * bflo(v1.x); a1 += e1 * bfhi(v1.x);
        a2 += e1 * bflo(v1.y); a3 += e1 * bfhi(v1.y);
        a4 += e1 * bflo(v1.z); a5 += e1 * bfhi(v1.z);
        a6 += e1 * bflo(v1.w); a7 += e1 * bfhi(v1.w);
        den += e0 + e1;
    }

    // combine the two halves (each processed every other edge)
    a0 += __shfl_xor(a0, 16, 32); a1 += __shfl_xor(a1, 16, 32);
    a2 += __shfl_xor(a2, 16, 32); a3 += __shfl_xor(a3, 16, 32);
    a4 += __shfl_xor(a4, 16, 32); a5 += __shfl_xor(a5, 16, 32);
    a6 += __shfl_xor(a6, 16, 32); a7 += __shfl_xor(a7, 16, 32);
    den += __shfl_xor(den, 16, 32);

    const float inv = 1.f / (den + EPS);

    // gather all 4 head denominators for the inv_den table (lane 0 stores)
    float d0 = __shfl(den, 0, 32);
    float d1 = __shfl(den, 4, 32);
    float d2 = __shfl(den, 8, 32);
    float d3 = __shfl(den, 12, 32);

    float4 o = half ? make_float4(a4 * inv, a5 * inv, a6 * inv, a7 * inv)
                    : make_float4(a0 * inv, a1 * inv, a2 * inv, a3 * inv);
    *(float4*)(out + (size_t)n * 128 + q * 8 + half * 4) = o;

    if (l == 0)
        *(float4*)(inv_den + (size_t)n * 4) =
            make_float4(1.f / (d0 + EPS), 1.f / (d1 + EPS),
                        1.f / (d2 + EPS), 1.f / (d3 + EPS));
}

// ---------------------------------------------------------------------------
// Kernel D: edge-order alpha, recomputed from the score tables (identical
// fp32 ops/order as node_aggr's es). Unchanged.
// ---------------------------------------------------------------------------
__global__ __launch_bounds__(256) void alpha_kernel(
    const int* __restrict__ src, const int* __restrict__ dst,
    const float* __restrict__ rnbrw,
    const float* __restrict__ s_src, const float* __restrict__ s_dst,
    const float* __restrict__ inv_den, float* __restrict__ alpha, int E)
{
    int e = blockIdx.x * 256 + threadIdx.x;
    if (e >= E) return;
    int s = src[e], d = dst[e];
    float lw = __logf(rnbrw[e] + EPS);
    float4 a = *(const float4*)(s_src + s * 4);
    float4 b = *(const float4*)(s_dst + d * 4);
    float4 iv = *(const float4*)(inv_den + (size_t)d * 4);
    float4 al;
    float v;
    v = a.x + b.x + lw; v = (v >= 0.f) ? v : 0.2f * v; al.x = __expf(v) * iv.x;
    v = a.y + b.y + lw; v = (v >= 0.f) ? v : 0.2f * v; al.y = __expf(v) * iv.y;
    v = a.z + b.z + lw; v = (v >= 0.f) ? v : 0.2f * v; al.z = __expf(v) * iv.z;
    v = a.w + b.w + lw; v = (v >= 0.f) ? v : 0.2f * v; al.w = __expf(v) * iv.w;
    *(float4*)(alpha + (size_t)e * 4) = al;
}

extern "C" void kernel_launch(void* const* d_in, const int* in_sizes, int n_in,
                              void* d_out, int out_size, void* d_ws, size_t ws_size,
                              hipStream_t stream) {
    const float* x      = (const float*)d_in[0];
    const float* W      = (const float*)d_in[1];
    const float* a_src  = (const float*)d_in[2];
    const float* a_dst  = (const float*)d_in[3];
    const int*   eidx   = (const int*)d_in[4];
    const float* rnbrw  = (const float*)d_in[5];

    const int E = in_sizes[5];           // 1600000
    const int N = in_sizes[0] / 128;     // 100000

    float* out   = (float*)d_out;                    // [N,128]
    float* alpha = out + (size_t)N * 128;            // [E,4] final alpha

    // Workspace layout (~44.5 MB, inside the proven 68.4 MB budget).
    char* w = (char*)d_ws;
    unsigned short* hb = (unsigned short*)w;  w += (size_t)N * 128 * 2;  // 25.6 MB
    int2* rec     = (int2*)w;                 w += (size_t)E * 8;        // 12.8 MB
    float* s_src  = (float*)w;                w += (size_t)N * 16;       //  1.6 MB
    float* s_dst  = (float*)w;                w += (size_t)N * 16;       //  1.6 MB
    float* inv_den = (float*)w;               w += (size_t)N * 16;       //  1.6 MB
    int* counts  = (int*)w;                   w += (size_t)N * 4;        //  0.4 MB
    int* offs    = (int*)w;                   w += (size_t)N * 4;        //  0.4 MB
    int* cursor  = (int*)w;                   w += (size_t)N * 4;        //  0.4 MB
    int* bsum    = (int*)w;                   w += 512 * 4;

    const int* src = eidx;
    const int* dst = eidx + E;

    hipMemsetAsync(counts, 0, (size_t)N * sizeof(int), stream);

    // One launch: 1024 gemm blocks + 512 count blocks, interleaved (bid%3)
    // so both roles co-reside from t=0. count hides under the VALU-bound gemm.
    int n_tiles = (N + 63) / 64;
    gemm_count_kernel<<<1536, 256, 0, stream>>>(
        x, W, a_src, a_dst, hb, s_src, s_dst, N, n_tiles, dst, counts, E);

    int nb = (N + 1023) / 1024;
    scan1_kernel<<<nb, 256, 0, stream>>>(counts, offs, bsum, N);
    scan2_kernel<<<1, 512, 0, stream>>>(bsum, nb);
    scan3_kernel<<<(N + 255) / 256, 256, 0, stream>>>(offs, bsum, cursor, N);

    // 8 shard classes x bps blocks; class s (intended XCD s) handles
    // dst in [s*ssz, (s+1)*ssz). Runs alone: needs a quiet L2.
    int ssz = (N + 7) / 8;
    int bps = 256;
    scatter_kernel<<<8 * bps, 256, 0, stream>>>(src, dst, rnbrw, cursor, rec, E, ssz, bps);

    int ablocks = ((size_t)N * 32 + 255) / 256;
    node_aggr_kernel<<<ablocks, 256, 0, stream>>>(offs, counts, rec, s_src, s_dst, hb,
                                                  inv_den, out, N);

    int eblocks = (E + 255) / 256;
    alpha_kernel<<<eblocks, 256, 0, stream>>>(src, dst, rnbrw, s_src, s_dst,
                                              inv_den, alpha, E);
}